// Round 1
// baseline (40.562 us; speedup 1.0000x reference)
//
#include <hip/hip_runtime.h>

// YOLO v1 loss, forward only.
// predictions/target: (N, 7, 7, 30) f32, D = 2*5 + 20.
// Output: scalar f32 loss.

constexpr int D = 30;
constexpr float INV_S = 1.0f / 7.0f;   // 1 / S_CELLS

__global__ void __launch_bounds__(256) yolo_stage1(
        const float* __restrict__ pred,
        const float* __restrict__ tgt,
        float* __restrict__ partial,
        int ncells) {
    int cell = blockIdx.x * 256 + threadIdx.x;
    float loss = 0.f;
    if (cell < ncells) {
        const float* p = pred + (size_t)cell * D;
        const float* t = tgt  + (size_t)cell * D;

        // ---- load the 2 boxes (10 floats) of each tensor via float2 ----
        float pb[10], tb[10];
#pragma unroll
        for (int j = 0; j < 5; ++j) {
            float2 v = *reinterpret_cast<const float2*>(p + 2 * j);
            pb[2 * j] = v.x; pb[2 * j + 1] = v.y;
            float2 w = *reinterpret_cast<const float2*>(t + 2 * j);
            tb[2 * j] = w.x; tb[2 * j + 1] = w.y;
        }

        // ---- class loss (20 floats each, streamed) ----
        float lcls = 0.f;
#pragma unroll
        for (int j = 0; j < 10; ++j) {
            float2 pc = *reinterpret_cast<const float2*>(p + 10 + 2 * j);
            float2 tc = *reinterpret_cast<const float2*>(t + 10 + 2 * j);
            float dx = pc.x - tc.x;
            float dy = pc.y - tc.y;
            lcls += dx * dx + dy * dy;
        }

        float m_obj   = (tb[4] >  0.f) ? 1.f : 0.f;
        float m_noobj = (tb[4] == 0.f) ? 1.f : 0.f;

        // ---- target box 0 corners (xyxy) ----
        float t_x1 = tb[0] * INV_S - 0.5f * tb[2];
        float t_y1 = tb[1] * INV_S - 0.5f * tb[3];
        float t_x2 = tb[0] * INV_S + 0.5f * tb[2];
        float t_y2 = tb[1] * INV_S + 0.5f * tb[3];
        float area_t = (t_x2 - t_x1) * (t_y2 - t_y1);

        // ---- IoU of both pred boxes vs target box 0 ----
        float iou0, iou1;
#pragma unroll
        for (int b = 0; b < 2; ++b) {
            float x = pb[5 * b + 0], y = pb[5 * b + 1];
            float w = pb[5 * b + 2], h = pb[5 * b + 3];
            float p_x1 = x * INV_S - 0.5f * w;
            float p_y1 = y * INV_S - 0.5f * h;
            float p_x2 = x * INV_S + 0.5f * w;
            float p_y2 = y * INV_S + 0.5f * h;
            float lt_x = fmaxf(p_x1, t_x1), lt_y = fmaxf(p_y1, t_y1);
            float rb_x = fminf(p_x2, t_x2), rb_y = fminf(p_y2, t_y2);
            float iw = fmaxf(rb_x - lt_x, 0.f);
            float ih = fmaxf(rb_y - lt_y, 0.f);
            float inter = iw * ih;
            float area_p = (p_x2 - p_x1) * (p_y2 - p_y1);
            float uni = area_p + area_t - inter;
            float r = inter / (uni + 1e-10f);
            if (b == 0) iou0 = r; else iou1 = r;
        }

        // jnp.argmax picks the FIRST max -> box 1 wins only on strict >
        bool r1 = iou1 > iou0;
        float max_iou = fmaxf(iou0, iou1);

        // responsible-box select with compile-time indices (stays in VGPRs)
        float prx = r1 ? pb[5] : pb[0];
        float pry = r1 ? pb[6] : pb[1];
        float prw = r1 ? pb[7] : pb[2];
        float prh = r1 ? pb[8] : pb[3];
        float prc = r1 ? pb[9] : pb[4];
        float trx = r1 ? tb[5] : tb[0];
        float try_ = r1 ? tb[6] : tb[1];
        float trw = r1 ? tb[7] : tb[2];
        float trh = r1 ? tb[8] : tb[3];

        float dx = prx - trx, dy = pry - try_;
        float dxy = dx * dx + dy * dy;
        float sw = sqrtf(prw) - sqrtf(trw);
        float sh = sqrtf(prh) - sqrtf(trh);
        float dwh = sw * sw + sh * sh;
        float doj = prc - max_iou;
        float dobj = doj * doj;
        float dn0 = pb[4] - tb[4];
        float dn1 = pb[9] - tb[9];
        float dnoobj = dn0 * dn0 + dn1 * dn1;

        loss = m_obj * (5.0f * (dxy + dwh) + dobj + lcls)
             + 0.5f * m_noobj * dnoobj;
    }

    // ---- block reduction: wave shuffle then LDS across 4 waves ----
#pragma unroll
    for (int off = 32; off > 0; off >>= 1)
        loss += __shfl_down(loss, off, 64);
    __shared__ float wsum[4];
    int lane = threadIdx.x & 63;
    int wid  = threadIdx.x >> 6;
    if (lane == 0) wsum[wid] = loss;
    __syncthreads();
    if (threadIdx.x == 0)
        partial[blockIdx.x] = wsum[0] + wsum[1] + wsum[2] + wsum[3];
}

__global__ void __launch_bounds__(1024) yolo_stage2(
        const float* __restrict__ partial, int n,
        float* __restrict__ out, float inv_n) {
    float s = 0.f;
    for (int i = threadIdx.x; i < n; i += 1024)
        s += partial[i];
#pragma unroll
    for (int off = 32; off > 0; off >>= 1)
        s += __shfl_down(s, off, 64);
    __shared__ float w[16];
    int lane = threadIdx.x & 63;
    int wid  = threadIdx.x >> 6;
    if (lane == 0) w[wid] = s;
    __syncthreads();
    if (threadIdx.x == 0) {
        float tot = 0.f;
#pragma unroll
        for (int i = 0; i < 16; ++i) tot += w[i];
        out[0] = tot * inv_n;
    }
}

extern "C" void kernel_launch(void* const* d_in, const int* in_sizes, int n_in,
                              void* d_out, int out_size, void* d_ws, size_t ws_size,
                              hipStream_t stream) {
    const float* pred = (const float*)d_in[0];
    const float* tgt  = (const float*)d_in[1];
    float* out     = (float*)d_out;
    float* partial = (float*)d_ws;

    int ncells  = in_sizes[0] / D;           // N * 7 * 7
    int nblocks = (ncells + 255) / 256;      // 3136 for N=16384
    float inv_n = 49.0f / (float)ncells;     // 1 / N

    yolo_stage1<<<nblocks, 256, 0, stream>>>(pred, tgt, partial, ncells);
    yolo_stage2<<<1, 1024, 0, stream>>>(partial, nblocks, out, inv_n);
}

// Round 2
// 36.508 us; speedup vs baseline: 1.1111x; 1.1111x over previous
//
#include <hip/hip_runtime.h>

// YOLO v1 loss, forward only.
// predictions/target: (N, 7, 7, 30) f32, D = 2*5 + 20.
// Output: scalar f32 loss.
//
// Strategy: per-cell direct loads are 120B-strided -> ~60 cache lines per
// wave instruction (line-split bound, ~70us). Instead, each 128-thread block
// stages its 128 cells (2 x 15360 B) into LDS with fully coalesced float4
// loads, then computes per-cell loss from LDS.

constexpr int D = 30;
constexpr int CPB = 128;                  // cells per block == threads per block
constexpr int F4_PER_TENSOR = CPB * D / 4; // 960 float4 per tensor per block
constexpr float INV_S = 1.0f / 7.0f;

__global__ void __launch_bounds__(CPB) yolo_stage1(
        const float* __restrict__ pred,
        const float* __restrict__ tgt,
        float* __restrict__ partial) {
    __shared__ float lp[CPB * D];
    __shared__ float lt[CPB * D];

    const float4* __restrict__ pv =
        reinterpret_cast<const float4*>(pred) + (size_t)blockIdx.x * F4_PER_TENSOR;
    const float4* __restrict__ tv =
        reinterpret_cast<const float4*>(tgt) + (size_t)blockIdx.x * F4_PER_TENSOR;

    // ---- coalesced staging: 7 full rounds + predicated tail (960 = 7.5*128)
#pragma unroll
    for (int k = 0; k < 7; ++k) {
        int i = threadIdx.x + k * CPB;
        float4 a = pv[i];
        float4 b = tv[i];
        *reinterpret_cast<float4*>(&lp[4 * i]) = a;
        *reinterpret_cast<float4*>(&lt[4 * i]) = b;
    }
    {
        int i = threadIdx.x + 7 * CPB;
        if (i < F4_PER_TENSOR) {
            float4 a = pv[i];
            float4 b = tv[i];
            *reinterpret_cast<float4*>(&lp[4 * i]) = a;
            *reinterpret_cast<float4*>(&lt[4 * i]) = b;
        }
    }
    __syncthreads();

    const float* p = &lp[threadIdx.x * D];
    const float* t = &lt[threadIdx.x * D];

    // ---- load the 2 boxes (10 floats) of each tensor via float2 (ds_read_b64)
    float pb[10], tb[10];
#pragma unroll
    for (int j = 0; j < 5; ++j) {
        float2 v = *reinterpret_cast<const float2*>(p + 2 * j);
        pb[2 * j] = v.x; pb[2 * j + 1] = v.y;
        float2 w = *reinterpret_cast<const float2*>(t + 2 * j);
        tb[2 * j] = w.x; tb[2 * j + 1] = w.y;
    }

    // ---- class loss (20 floats each) ----
    float lcls = 0.f;
#pragma unroll
    for (int j = 0; j < 10; ++j) {
        float2 pc = *reinterpret_cast<const float2*>(p + 10 + 2 * j);
        float2 tc = *reinterpret_cast<const float2*>(t + 10 + 2 * j);
        float dx = pc.x - tc.x;
        float dy = pc.y - tc.y;
        lcls += dx * dx + dy * dy;
    }

    float m_obj   = (tb[4] >  0.f) ? 1.f : 0.f;
    float m_noobj = (tb[4] == 0.f) ? 1.f : 0.f;

    // ---- target box 0 corners (xyxy) ----
    float t_x1 = tb[0] * INV_S - 0.5f * tb[2];
    float t_y1 = tb[1] * INV_S - 0.5f * tb[3];
    float t_x2 = tb[0] * INV_S + 0.5f * tb[2];
    float t_y2 = tb[1] * INV_S + 0.5f * tb[3];
    float area_t = (t_x2 - t_x1) * (t_y2 - t_y1);

    // ---- IoU of both pred boxes vs target box 0 ----
    float iou0, iou1;
#pragma unroll
    for (int b = 0; b < 2; ++b) {
        float x = pb[5 * b + 0], y = pb[5 * b + 1];
        float w = pb[5 * b + 2], h = pb[5 * b + 3];
        float p_x1 = x * INV_S - 0.5f * w;
        float p_y1 = y * INV_S - 0.5f * h;
        float p_x2 = x * INV_S + 0.5f * w;
        float p_y2 = y * INV_S + 0.5f * h;
        float lt_x = fmaxf(p_x1, t_x1), lt_y = fmaxf(p_y1, t_y1);
        float rb_x = fminf(p_x2, t_x2), rb_y = fminf(p_y2, t_y2);
        float iw = fmaxf(rb_x - lt_x, 0.f);
        float ih = fmaxf(rb_y - lt_y, 0.f);
        float inter = iw * ih;
        float area_p = (p_x2 - p_x1) * (p_y2 - p_y1);
        float uni = area_p + area_t - inter;
        float r = inter / (uni + 1e-10f);
        if (b == 0) iou0 = r; else iou1 = r;
    }

    // jnp.argmax picks the FIRST max -> box 1 wins only on strict >
    bool r1 = iou1 > iou0;
    float max_iou = fmaxf(iou0, iou1);

    float prx = r1 ? pb[5] : pb[0];
    float pry = r1 ? pb[6] : pb[1];
    float prw = r1 ? pb[7] : pb[2];
    float prh = r1 ? pb[8] : pb[3];
    float prc = r1 ? pb[9] : pb[4];
    float trx = r1 ? tb[5] : tb[0];
    float try_ = r1 ? tb[6] : tb[1];
    float trw = r1 ? tb[7] : tb[2];
    float trh = r1 ? tb[8] : tb[3];

    float dx = prx - trx, dy = pry - try_;
    float dxy = dx * dx + dy * dy;
    float sw = sqrtf(prw) - sqrtf(trw);
    float sh = sqrtf(prh) - sqrtf(trh);
    float dwh = sw * sw + sh * sh;
    float doj = prc - max_iou;
    float dobj = doj * doj;
    float dn0 = pb[4] - tb[4];
    float dn1 = pb[9] - tb[9];
    float dnoobj = dn0 * dn0 + dn1 * dn1;

    float loss = m_obj * (5.0f * (dxy + dwh) + dobj + lcls)
               + 0.5f * m_noobj * dnoobj;

    // ---- block reduction: wave shuffle then LDS across 2 waves ----
#pragma unroll
    for (int off = 32; off > 0; off >>= 1)
        loss += __shfl_down(loss, off, 64);
    __shared__ float wsum[2];
    int lane = threadIdx.x & 63;
    int wid  = threadIdx.x >> 6;
    if (lane == 0) wsum[wid] = loss;
    __syncthreads();
    if (threadIdx.x == 0)
        partial[blockIdx.x] = wsum[0] + wsum[1];
}

__global__ void __launch_bounds__(1024) yolo_stage2(
        const float* __restrict__ partial, int n,
        float* __restrict__ out, float inv_n) {
    float s = 0.f;
    for (int i = threadIdx.x; i < n; i += 1024)
        s += partial[i];
#pragma unroll
    for (int off = 32; off > 0; off >>= 1)
        s += __shfl_down(s, off, 64);
    __shared__ float w[16];
    int lane = threadIdx.x & 63;
    int wid  = threadIdx.x >> 6;
    if (lane == 0) w[wid] = s;
    __syncthreads();
    if (threadIdx.x == 0) {
        float tot = 0.f;
#pragma unroll
        for (int i = 0; i < 16; ++i) tot += w[i];
        out[0] = tot * inv_n;
    }
}

extern "C" void kernel_launch(void* const* d_in, const int* in_sizes, int n_in,
                              void* d_out, int out_size, void* d_ws, size_t ws_size,
                              hipStream_t stream) {
    const float* pred = (const float*)d_in[0];
    const float* tgt  = (const float*)d_in[1];
    float* out     = (float*)d_out;
    float* partial = (float*)d_ws;

    int ncells  = in_sizes[0] / D;           // N * 7 * 7 = 802816
    int nblocks = ncells / CPB;              // 6272 (divides exactly)
    float inv_n = 49.0f / (float)ncells;     // 1 / N

    yolo_stage1<<<nblocks, CPB, 0, stream>>>(pred, tgt, partial);
    yolo_stage2<<<1, 1024, 0, stream>>>(partial, nblocks, out, inv_n);
}